// Round 13
// baseline (233.687 us; speedup 1.0000x reference)
//
#include <hip/hip_runtime.h>
#include <hip/hip_fp16.h>
#include <math.h>
#include <stdint.h>

#define BB 32
#define NN 512
#define DDIM 512
#define HH 8
#define DK 64

typedef __attribute__((ext_vector_type(8))) short short8;
typedef __attribute__((ext_vector_type(8))) _Float16 half8;
typedef __attribute__((ext_vector_type(4))) float floatx4;
typedef __attribute__((ext_vector_type(16))) float floatx16;
typedef unsigned short ushort_t;
typedef unsigned int uint_t;

// async global->LDS, 16B/lane; LDS dest = wave-uniform base + lane*16
__device__ __forceinline__ void gl_lds16(const void* g, void* l) {
    __builtin_amdgcn_global_load_lds(
        (const __attribute__((address_space(1))) uint_t*)g,
        (__attribute__((address_space(3))) uint_t*)l,
        16, 0, 0);
}

__device__ __forceinline__ ushort_t f2bf(float f) {  // RNE fp32->bf16
    uint_t u = __builtin_bit_cast(uint_t, f);
    u += 0x7fff + ((u >> 16) & 1);
    return (ushort_t)(u >> 16);
}

__device__ __forceinline__ uint_t pkbf(float a, float b) {
    return (uint_t)f2bf(a) | ((uint_t)f2bf(b) << 16);
}

__device__ __forceinline__ uint_t pkh(float a, float b) {  // 2xf32 -> f16x2 (RTZ, 1 inst)
    return __builtin_bit_cast(uint_t, __builtin_amdgcn_cvt_pkrtz(a, b));
}

__device__ __forceinline__ float h2f(ushort_t u) {
    return __half2float(__ushort_as_half(u));
}

// ---------------------------------------------------------------------------
// merged prep kernel: blockIdx.x partition
// ---------------------------------------------------------------------------
__global__ __launch_bounds__(256) void prep_all(
    const float* __restrict__ x, const float* __restrict__ dist,
    const float* __restrict__ dw,
    const float* __restrict__ Wq, const float* __restrict__ Wk,
    const float* __restrict__ Wv, const float* __restrict__ Wo,
    ushort_t* __restrict__ xb, ushort_t* __restrict__ Tm,
    ushort_t* __restrict__ wqb, ushort_t* __restrict__ wkb,
    ushort_t* __restrict__ wvb, ushort_t* __restrict__ wob) {
    const int bx = blockIdx.x;
    if (bx < 4096) {
        const int i = bx * 256 + threadIdx.x;
        const float4 a = ((const float4*)x)[i * 2 + 0];
        const float4 b = ((const float4*)x)[i * 2 + 1];
        uint4 o;
        o.x = pkbf(a.x, a.y); o.y = pkbf(a.z, a.w);
        o.z = pkbf(b.x, b.y); o.w = pkbf(b.z, b.w);
        *(uint4*)(xb + (size_t)i * 8) = o;
    } else if (bx < 8192) {
        __shared__ float dws[21];
        if (threadIdx.x < 21) dws[threadIdx.x] = (dw[threadIdx.x] - 3.0f) * 1.44269504f;
        __syncthreads();
        const int i = (bx - 4096) * 256 + threadIdx.x;
        float dv[8];
        { const float4 a = ((const float4*)dist)[i * 2 + 0];
          const float4 b = ((const float4*)dist)[i * 2 + 1];
          dv[0]=a.x; dv[1]=a.y; dv[2]=a.z; dv[3]=a.w;
          dv[4]=b.x; dv[5]=b.y; dv[6]=b.z; dv[7]=b.w; }
        ushort_t h[8];
        #pragma unroll
        for (int j = 0; j < 8; ++j) {
            int bin = (int)(dv[j] / 5.0f);
            bin = bin < 0 ? 0 : (bin > 20 ? 20 : bin);
            h[j] = __half_as_ushort(__float2half(dws[bin]));
        }
        uint4 o;
        o.x = (uint_t)h[0] | ((uint_t)h[1] << 16);
        o.y = (uint_t)h[2] | ((uint_t)h[3] << 16);
        o.z = (uint_t)h[4] | ((uint_t)h[5] << 16);
        o.w = (uint_t)h[6] | ((uint_t)h[7] << 16);
        *(uint4*)(Tm + (size_t)i * 8) = o;
    } else {
        const int bw = bx - 8192;            // [0,512)
        const int w = bw >> 7;               // matrix id
        const float* s; ushort_t* d;
        if (w == 0)      { s = Wq; d = wqb; }
        else if (w == 1) { s = Wk; d = wkb; }
        else if (w == 2) { s = Wv; d = wvb; }
        else             { s = Wo; d = wob; }
        const int i = (bw & 127) * 256 + threadIdx.x;
        const float4 a = ((const float4*)s)[i * 2 + 0];
        const float4 b = ((const float4*)s)[i * 2 + 1];
        uint4 o;
        o.x = pkbf(a.x, a.y); o.y = pkbf(a.z, a.w);
        o.z = pkbf(b.x, b.y); o.w = pkbf(b.z, b.w);
        *(uint4*)(d + (size_t)i * 8) = o;
    }
}

// ---------------------------------------------------------------------------
// GEMM core (round-7 proven, best total): D[feat][token] = W x A^T.
// 128x128 tile, BK=32, global_load_lds, XOR chunk swizzle, 16KB LDS.
// NOTE (round-6): no XCD remap on GEMM grids (FETCH 29->100MB, +15us).
// NOTE (rounds 3/8/11): BK=64 dbuf, counted-vmcnt, and single-barrier
// 2-phase all null-to-negative on this 4-wave 128^2 shape — T3/T4 needs
// the deep 8-phase schedule to pay (catalog regime gate). Keep 2-barrier.
// ---------------------------------------------------------------------------
#define GEMM_CORE(Aptr, Wptr, M0, N0)                                                   \
    __shared__ ushort_t SH[2][128 * 32];                                                \
    ushort_t* const As = SH[0];                                                         \
    ushort_t* const Bs = SH[1];                                                         \
    const int tid = threadIdx.x;                                                        \
    const int lane = tid & 63, wid = tid >> 6;                                          \
    const int quad = lane >> 4, l15 = lane & 15;                                        \
    const int m0 = (M0), n0 = (N0);                                                     \
    const int wy = wid >> 1, wx = wid & 1;                                              \
    floatx4 acc[4][4];                                                                  \
    _Pragma("unroll") for (int i = 0; i < 4; ++i)                                       \
        _Pragma("unroll") for (int j = 0; j < 4; ++j)                                   \
            _Pragma("unroll") for (int r = 0; r < 4; ++r) acc[i][j][r] = 0.f;           \
    for (int k0 = 0; k0 < DDIM; k0 += 32) {                                             \
        __syncthreads();                                                                \
        _Pragma("unroll") for (int j = 0; j < 4; ++j) {                                 \
            const int t = wid * 4 + j;                                                  \
            const int rowi = ((t & 7) << 4) + (lane >> 2);                              \
            const int cd = (lane & 3) ^ ((rowi >> 1) & 3);                              \
            if (t < 8)                                                                  \
                gl_lds16(Aptr + (size_t)(m0 + rowi) * DDIM + k0 + cd * 8,               \
                         (char*)As + ((t & 7) << 10));                                  \
            else                                                                        \
                gl_lds16(Wptr + (size_t)(n0 + rowi) * DDIM + k0 + cd * 8,               \
                         (char*)Bs + ((t & 7) << 10));                                  \
        }                                                                               \
        __syncthreads();                                                                \
        short8 aw[4], bt[4];                                                            \
        _Pragma("unroll") for (int fi = 0; fi < 4; ++fi) {                              \
            const int r = wy * 64 + fi * 16 + l15;                                      \
            aw[fi] = *(const short8*)((const char*)Bs + r * 64 +                        \
                                      ((quad ^ ((r >> 1) & 3)) << 4));                  \
        }                                                                               \
        _Pragma("unroll") for (int ti = 0; ti < 4; ++ti) {                              \
            const int r = wx * 64 + ti * 16 + l15;                                      \
            bt[ti] = *(const short8*)((const char*)As + r * 64 +                        \
                                      ((quad ^ ((r >> 1) & 3)) << 4));                  \
        }                                                                               \
        _Pragma("unroll") for (int fi = 0; fi < 4; ++fi)                                \
            _Pragma("unroll") for (int ti = 0; ti < 4; ++ti)                            \
                acc[fi][ti] = __builtin_amdgcn_mfma_f32_16x16x32_bf16(                  \
                    aw[fi], bt[ti], acc[fi][ti], 0, 0, 0);                              \
    }

// QKV projection -> Q,K bf16 [token][512]; V (z==2) written transposed as
// fp16 Vt[(b*8+h)*64+d][token] via 16KB LDS transpose (reuses SH).
__global__ __launch_bounds__(256) void gemm_qkv(
    const ushort_t* __restrict__ A,
    const ushort_t* __restrict__ W0, const ushort_t* __restrict__ W1,
    const ushort_t* __restrict__ W2,
    const float* __restrict__ b0, const float* __restrict__ b1,
    const float* __restrict__ b2,
    ushort_t* __restrict__ o0, ushort_t* __restrict__ o1, ushort_t* __restrict__ o2) {
    const ushort_t* W; const float* bias; ushort_t* dst;
    if (blockIdx.z == 0)      { W = W0; bias = b0; dst = o0; }
    else if (blockIdx.z == 1) { W = W1; bias = b1; dst = o1; }
    else                      { W = W2; bias = b2; dst = o2; }
    const bool as_f16 = (blockIdx.z == 2);
    GEMM_CORE(A, W, blockIdx.x * 128, blockIdx.y * 128)
    if (as_f16) {
        const int b = m0 >> 9;            // batch (tile within one b)
        const int hh0 = n0 >> 6;          // head of wy==0 half
        ushort_t* const SHT = &SH[0][0];  // 16KB = [64][128] fp16, chunk-swizzled
        __syncthreads();                  // all K-loop LDS reads complete
        #pragma unroll
        for (int hp = 0; hp < 2; ++hp) {
            if (wy == hp) {
                #pragma unroll
                for (int fi = 0; fi < 4; ++fi) {
                    const int f = n0 + wy * 64 + fi * 16 + quad * 4;
                    const float4 b4 = *(const float4*)&bias[f];
                    #pragma unroll
                    for (int ti = 0; ti < 4; ++ti) {
                        const int q = wx * 64 + ti * 16 + l15;
                        const int qc = q >> 3, qr = q & 7;
                        const float vv[4] = {acc[fi][ti][0] + b4.x,
                                             acc[fi][ti][1] + b4.y,
                                             acc[fi][ti][2] + b4.z,
                                             acc[fi][ti][3] + b4.w};
                        #pragma unroll
                        for (int r = 0; r < 4; ++r) {
                            const int d = fi * 16 + quad * 4 + r;
                            SHT[(d * 256 + ((qc ^ (d & 15)) << 4) + qr * 2) >> 1] =
                                __half_as_ushort(__float2half(vv[r]));
                        }
                    }
                }
            }
            __syncthreads();
            const size_t vbase = ((size_t)(b * HH + hh0 + hp)) * DK;
            #pragma unroll
            for (int c = 0; c < 4; ++c) {
                const int ch = tid + 256 * c;           // [0,1024)
                const int d = ch >> 4, chl = ch & 15;
                const uint4 vv = *(const uint4*)((const char*)SHT + d * 256 +
                                                 ((chl ^ (d & 15)) << 4));
                *(uint4*)&dst[(vbase + d) * NN + (m0 & 511) + chl * 8] = vv;
            }
            __syncthreads();
        }
    } else {
        #pragma unroll
        for (int fi = 0; fi < 4; ++fi) {
            const int f = n0 + wy * 64 + fi * 16 + quad * 4;
            const float4 b4 = *(const float4*)&bias[f];
            #pragma unroll
            for (int ti = 0; ti < 4; ++ti) {
                const int token = m0 + wx * 64 + ti * 16 + l15;
                const float v0 = acc[fi][ti][0] + b4.x, v1 = acc[fi][ti][1] + b4.y;
                const float v2 = acc[fi][ti][2] + b4.z, v3 = acc[fi][ti][3] + b4.w;
                uint2 v;
                v.x = pkbf(v0, v1); v.y = pkbf(v2, v3);
                *(uint2*)&dst[(size_t)token * DDIM + f] = v;
            }
        }
    }
}

// Output projection -> fp32 [token][512]
__global__ __launch_bounds__(256) void gemm_out(
    const ushort_t* __restrict__ A, const ushort_t* __restrict__ Wo,
    const float* __restrict__ bo, float* __restrict__ dst) {
    GEMM_CORE(A, Wo, blockIdx.x * 128, blockIdx.y * 128)
    #pragma unroll
    for (int fi = 0; fi < 4; ++fi) {
        const int f = n0 + wy * 64 + fi * 16 + quad * 4;
        const float4 b4 = *(const float4*)&bo[f];
        #pragma unroll
        for (int ti = 0; ti < 4; ++ti) {
            const int token = m0 + wx * 64 + ti * 16 + l15;
            float4 v;
            v.x = acc[fi][ti][0] + b4.x; v.y = acc[fi][ti][1] + b4.y;
            v.z = acc[fi][ti][2] + b4.z; v.w = acc[fi][ti][3] + b4.w;
            *(float4*)&dst[(size_t)token * DDIM + f] = v;
        }
    }
}

// ---------------------------------------------------------------------------
// Persistent-KV MFMA attention, 32x32 MFMA + in-register P.
// XCD swizzle (round-7 A/B, -4.4us): h = n&7, b = n>>3 with n = (p%8)*32+p/8
// -> all 8 heads of one b on ONE XCD, T[b] L2-resident.
// Round-12: T-load software pipeline (T14). The kt loop is macro-unrolled
// into 8 static bodies with TWO named tv register buffers ping-ponged by
// parity (all indices compile-time — no scratch). Body kt issues kt+1's 16
// T-loads FIRST, then computes kt — the L2 latency (~200-300cyc) hides
// under ~1500+cyc of MFMA/VALU/exp instead of stalling softmax each kt.
// +~32 VGPR (within the 256 budget at 2 waves/SIMD).
// ---------------------------------------------------------------------------
#define LOAD_TV(DST, KT)                                                            \
    _Pragma("unroll")                                                               \
    for (int qt = 0; qt < 2; ++qt) {                                                \
        const ushort_t* tp = Tg +                                                   \
            (size_t)(b * NN + wid * 64 + qt * 32 + l31) * NN + (KT) * 64 + hl * 4;  \
        _Pragma("unroll")                                                           \
        for (int kti = 0; kti < 2; ++kti)                                           \
            _Pragma("unroll")                                                       \
            for (int g = 0; g < 4; ++g)                                             \
                DST[qt][kti][g] = *(const uint2*)(tp + kti * 32 + g * 8);           \
    }

#define KT_STEP(KT, TVC, TVN, PREF)                                                 \
    {                                                                               \
        if (PREF) { LOAD_TV(TVN, (KT) + 1) }                                        \
        _Pragma("unroll")                                                           \
        for (int kti = 0; kti < 2; ++kti) {                                         \
            short8 kf[4];                                                           \
            {                                                                       \
                const int row = (KT) * 64 + kti * 32 + l31;                         \
                const int key = (row & 7) ^ ((row >> 3) & 7);                       \
                _Pragma("unroll")                                                   \
                for (int st = 0; st < 4; ++st)                                      \
                    kf[st] = *(const short8*)((const char*)Ks + row * 128 +         \
                                              (((st * 2 + hl) ^ key) << 4));        \
            }                                                                       \
            half8 vf[2][2];                                                         \
            _Pragma("unroll")                                                       \
            for (int dt = 0; dt < 2; ++dt) {                                        \
                const int d = dt * 32 + l31;                                        \
                const int key = (d & 7) ^ ((d >> 3) & 7);                           \
                _Pragma("unroll")                                                   \
                for (int ks = 0; ks < 2; ++ks)                                      \
                    vf[dt][ks] = *(const half8*)((const char*)Vs + d * 1024 +       \
                        ((((KT) * 8 + kti * 4 + ks * 2 + hl) ^ key) << 4));         \
            }                                                                       \
            _Pragma("unroll")                                                       \
            for (int qt = 0; qt < 2; ++qt) {                                        \
                floatx16 S;                                                         \
                _Pragma("unroll")                                                   \
                for (int r = 0; r < 16; ++r) S[r] = 0.f;                            \
                __builtin_amdgcn_s_setprio(1);                                      \
                _Pragma("unroll")                                                   \
                for (int st = 0; st < 4; ++st)                                      \
                    S = __builtin_amdgcn_mfma_f32_32x32x16_bf16(                    \
                        kf[st], bq[qt][st], S, 0, 0, 0);                            \
                __builtin_amdgcn_s_setprio(0);                                      \
                float ls = 0.f;                                                     \
                _Pragma("unroll")                                                   \
                for (int ks = 0; ks < 2; ++ks) {                                    \
                    float pp[8];                                                    \
                    _Pragma("unroll")                                               \
                    for (int gg = 0; gg < 2; ++gg) {                                \
                        const uint2 tg = TVC[qt][kti][ks * 2 + gg];                 \
                        const float t0 = h2f((ushort_t)tg.x);                       \
                        const float t1 = h2f((ushort_t)(tg.x >> 16));               \
                        const float t2 = h2f((ushort_t)tg.y);                       \
                        const float t3 = h2f((ushort_t)(tg.y >> 16));               \
                        const int sb = ks * 8 + gg * 4;                             \
                        pp[gg * 4 + 0] = exp2f(S[sb + 0] * K1 + t0);                \
                        pp[gg * 4 + 1] = exp2f(S[sb + 1] * K1 + t1);                \
                        pp[gg * 4 + 2] = exp2f(S[sb + 2] * K1 + t2);                \
                        pp[gg * 4 + 3] = exp2f(S[sb + 3] * K1 + t3);                \
                        ls += (pp[gg * 4 + 0] + pp[gg * 4 + 1]) +                   \
                              (pp[gg * 4 + 2] + pp[gg * 4 + 3]);                    \
                    }                                                               \
                    uint_t w0 = pkh(pp[0], pp[1]);                                  \
                    uint_t w1 = pkh(pp[2], pp[3]);                                  \
                    uint_t w2 = pkh(pp[4], pp[5]);                                  \
                    uint_t w3 = pkh(pp[6], pp[7]);                                  \
                    auto r02 = __builtin_amdgcn_permlane32_swap(w0, w2, false, false); \
                    auto r13 = __builtin_amdgcn_permlane32_swap(w1, w3, false, false); \
                    uint4 uu;                                                       \
                    uu.x = r02[0]; uu.y = r13[0]; uu.z = r02[1]; uu.w = r13[1];     \
                    const half8 bp = __builtin_bit_cast(half8, uu);                 \
                    __builtin_amdgcn_s_setprio(1);                                  \
                    _Pragma("unroll")                                               \
                    for (int dt = 0; dt < 2; ++dt)                                  \
                        O[qt][dt] = __builtin_amdgcn_mfma_f32_32x32x16_f16(         \
                            vf[dt][ks], bp, O[qt][dt], 0, 0, 0);                    \
                    __builtin_amdgcn_s_setprio(0);                                  \
                }                                                                   \
                lsum[qt] += ls;                                                     \
            }                                                                       \
        }                                                                           \
    }

__global__ __launch_bounds__(512)
__attribute__((amdgpu_waves_per_eu(2, 2)))
void attn_fused(
    const ushort_t* __restrict__ Qg, const ushort_t* __restrict__ Kg,
    const ushort_t* __restrict__ Vtg, const ushort_t* __restrict__ Tg,
    ushort_t* __restrict__ aout) {
    __shared__ ushort_t Ks[512 * 64];   // 64KB: row kj, 128B, 8x16B grans, gran g = global g^key(kj)
    __shared__ ushort_t Vs[64 * 512];   // 64KB: row d, 1024B, 64 grans, gran g = global g^key(d)

    const int tid = threadIdx.x, lane = tid & 63, wid = tid >> 6;
    const int l31 = lane & 31, hl = lane >> 5;
    const int p = blockIdx.x;
    const int nid = (p & 7) * 32 + (p >> 3);
    const int h = nid & 7, b = nid >> 3;
    const float K1 = 0.18033688f;       // 0.125 * log2(e)

    // ---- stage K + V^T (once) ----
    #pragma unroll
    for (int j = 0; j < 8; ++j) {
        const int t = wid * 8 + j;
        {   // K rows t*8 .. t*8+7 (1KB per wave-load)
            const int row = t * 8 + (lane >> 3);
            const int key = (row & 7) ^ ((row >> 3) & 7);
            const int g = (lane & 7) ^ key;
            gl_lds16(Kg + (size_t)(b * NN + row) * DDIM + h * DK + g * 8,
                     (char*)Ks + t * 1024);
        }
        {   // V^T row d = t (1KB per wave-load)
            const int key = (t & 7) ^ ((t >> 3) & 7);
            const int g = lane ^ key;
            gl_lds16(Vtg + (size_t)((b * HH + h) * DK + t) * NN + g * 8,
                     (char*)Vs + t * 1024);
        }
    }

    // ---- Q fragments (B-operand: n=q=lane&31, k=dk=(lane>>5)*8+j) ----
    short8 bq[2][4];
    #pragma unroll
    for (int qt = 0; qt < 2; ++qt) {
        const ushort_t* qp =
            Qg + (size_t)(b * NN + wid * 64 + qt * 32 + l31) * DDIM + h * DK + hl * 8;
        #pragma unroll
        for (int st = 0; st < 4; ++st) bq[qt][st] = *(const short8*)(qp + st * 16);
    }

    float lsum[2] = {0.f, 0.f};
    floatx16 O[2][2];                    // [qt][dt], C: col=q, row=d
    #pragma unroll
    for (int qt = 0; qt < 2; ++qt)
        #pragma unroll
        for (int dt = 0; dt < 2; ++dt)
            #pragma unroll
            for (int r = 0; r < 16; ++r) O[qt][dt][r] = 0.f;

    uint2 tva[2][2][4], tvb[2][2][4];    // T double buffer (ping-pong by parity)
    LOAD_TV(tva, 0)

    __syncthreads();   // the only barrier

    KT_STEP(0, tva, tvb, 1)
    KT_STEP(1, tvb, tva, 1)
    KT_STEP(2, tva, tvb, 1)
    KT_STEP(3, tvb, tva, 1)
    KT_STEP(4, tva, tvb, 1)
    KT_STEP(5, tvb, tva, 1)
    KT_STEP(6, tva, tvb, 1)
    KT_STEP(7, tvb, tva, 0)

    // ---- epilogue: reduce l over lane halves, normalize, write bf16 ----
    #pragma unroll
    for (int qt = 0; qt < 2; ++qt) {
        float l = lsum[qt];
        l += __shfl_xor(l, 32);
        const float inv = 1.0f / l;
        const size_t orow =
            (size_t)(b * NN + wid * 64 + qt * 32 + l31) * DDIM + h * DK;
        #pragma unroll
        for (int dt = 0; dt < 2; ++dt)
            #pragma unroll
            for (int g = 0; g < 4; ++g) {
                const int d = dt * 32 + g * 8 + hl * 4;
                uint2 ov;
                ov.x = pkbf(O[qt][dt][g * 4 + 0] * inv, O[qt][dt][g * 4 + 1] * inv);
                ov.y = pkbf(O[qt][dt][g * 4 + 2] * inv, O[qt][dt][g * 4 + 3] * inv);
                *(uint2*)&aout[orow + d] = ov;
            }
    }
}

extern "C" void kernel_launch(void* const* d_in, const int* in_sizes, int n_in,
                              void* d_out, int out_size, void* d_ws, size_t ws_size,
                              hipStream_t stream) {
    const float* x    = (const float*)d_in[0];
    const float* dist = (const float*)d_in[1];
    const float* Wq   = (const float*)d_in[2];
    const float* bq   = (const float*)d_in[3];
    const float* Wk   = (const float*)d_in[4];
    const float* bk   = (const float*)d_in[5];
    const float* Wv   = (const float*)d_in[6];
    const float* bv   = (const float*)d_in[7];
    const float* Wo   = (const float*)d_in[8];
    const float* bo   = (const float*)d_in[9];
    const float* dw   = (const float*)d_in[10];
    float* out = (float*)d_out;

    const size_t NELT = (size_t)BB * NN * DDIM;   // 8388608
    ushort_t* xb  = (ushort_t*)d_ws;              // x bf16; aliased by ab later
    ushort_t* wqb = xb + NELT;
    ushort_t* wkb = wqb + DDIM * DDIM;
    ushort_t* wvb = wkb + DDIM * DDIM;
    ushort_t* wob = wvb + DDIM * DDIM;
    ushort_t* qb  = wob + DDIM * DDIM;
    ushort_t* kb  = qb + NELT;
    ushort_t* vt  = kb + NELT;                    // fp16, transposed (written by gemm_qkv)
    ushort_t* Tm  = vt + NELT;                    // fp16 bias matrix
    ushort_t* ab  = xb;                           // alias: xb dead after gemm_qkv

    prep_all<<<8704, 256, 0, stream>>>(x, dist, dw, Wq, Wk, Wv, Wo,
                                       xb, Tm, wqb, wkb, wvb, wob);
    gemm_qkv<<<dim3(128, 4, 3), 256, 0, stream>>>(xb, wqb, wkb, wvb, bq, bk, bv,
                                                  qb, kb, vt);
    attn_fused<<<256, 512, 0, stream>>>(qb, kb, vt, Tm, ab);
    gemm_out<<<dim3(128, 4), 256, 0, stream>>>(ab, wob, bo, out);
}

// Round 14
// 224.899 us; speedup vs baseline: 1.0391x; 1.0391x over previous
//
#include <hip/hip_runtime.h>
#include <hip/hip_fp16.h>
#include <math.h>
#include <stdint.h>

#define BB 32
#define NN 512
#define DDIM 512
#define HH 8
#define DK 64

typedef __attribute__((ext_vector_type(8))) short short8;
typedef __attribute__((ext_vector_type(8))) _Float16 half8;
typedef __attribute__((ext_vector_type(4))) float floatx4;
typedef __attribute__((ext_vector_type(16))) float floatx16;
typedef unsigned short ushort_t;
typedef unsigned int uint_t;

// async global->LDS, 16B/lane; LDS dest = wave-uniform base + lane*16
__device__ __forceinline__ void gl_lds16(const void* g, void* l) {
    __builtin_amdgcn_global_load_lds(
        (const __attribute__((address_space(1))) uint_t*)g,
        (__attribute__((address_space(3))) uint_t*)l,
        16, 0, 0);
}

__device__ __forceinline__ ushort_t f2bf(float f) {  // RNE fp32->bf16
    uint_t u = __builtin_bit_cast(uint_t, f);
    u += 0x7fff + ((u >> 16) & 1);
    return (ushort_t)(u >> 16);
}

__device__ __forceinline__ uint_t pkbf(float a, float b) {
    return (uint_t)f2bf(a) | ((uint_t)f2bf(b) << 16);
}

__device__ __forceinline__ uint_t pkh(float a, float b) {  // 2xf32 -> f16x2 (RTZ, 1 inst)
    return __builtin_bit_cast(uint_t, __builtin_amdgcn_cvt_pkrtz(a, b));
}

__device__ __forceinline__ float h2f(ushort_t u) {
    return __half2float(__ushort_as_half(u));
}

// ---------------------------------------------------------------------------
// merged prep kernel: blockIdx.x partition
// ---------------------------------------------------------------------------
__global__ __launch_bounds__(256) void prep_all(
    const float* __restrict__ x, const float* __restrict__ dist,
    const float* __restrict__ dw,
    const float* __restrict__ Wq, const float* __restrict__ Wk,
    const float* __restrict__ Wv, const float* __restrict__ Wo,
    ushort_t* __restrict__ xb, ushort_t* __restrict__ Tm,
    ushort_t* __restrict__ wqb, ushort_t* __restrict__ wkb,
    ushort_t* __restrict__ wvb, ushort_t* __restrict__ wob) {
    const int bx = blockIdx.x;
    if (bx < 4096) {
        const int i = bx * 256 + threadIdx.x;
        const float4 a = ((const float4*)x)[i * 2 + 0];
        const float4 b = ((const float4*)x)[i * 2 + 1];
        uint4 o;
        o.x = pkbf(a.x, a.y); o.y = pkbf(a.z, a.w);
        o.z = pkbf(b.x, b.y); o.w = pkbf(b.z, b.w);
        *(uint4*)(xb + (size_t)i * 8) = o;
    } else if (bx < 8192) {
        __shared__ float dws[21];
        if (threadIdx.x < 21) dws[threadIdx.x] = (dw[threadIdx.x] - 3.0f) * 1.44269504f;
        __syncthreads();
        const int i = (bx - 4096) * 256 + threadIdx.x;
        float dv[8];
        { const float4 a = ((const float4*)dist)[i * 2 + 0];
          const float4 b = ((const float4*)dist)[i * 2 + 1];
          dv[0]=a.x; dv[1]=a.y; dv[2]=a.z; dv[3]=a.w;
          dv[4]=b.x; dv[5]=b.y; dv[6]=b.z; dv[7]=b.w; }
        ushort_t h[8];
        #pragma unroll
        for (int j = 0; j < 8; ++j) {
            int bin = (int)(dv[j] / 5.0f);
            bin = bin < 0 ? 0 : (bin > 20 ? 20 : bin);
            h[j] = __half_as_ushort(__float2half(dws[bin]));
        }
        uint4 o;
        o.x = (uint_t)h[0] | ((uint_t)h[1] << 16);
        o.y = (uint_t)h[2] | ((uint_t)h[3] << 16);
        o.z = (uint_t)h[4] | ((uint_t)h[5] << 16);
        o.w = (uint_t)h[6] | ((uint_t)h[7] << 16);
        *(uint4*)(Tm + (size_t)i * 8) = o;
    } else {
        const int bw = bx - 8192;            // [0,512)
        const int w = bw >> 7;               // matrix id
        const float* s; ushort_t* d;
        if (w == 0)      { s = Wq; d = wqb; }
        else if (w == 1) { s = Wk; d = wkb; }
        else if (w == 2) { s = Wv; d = wvb; }
        else             { s = Wo; d = wob; }
        const int i = (bw & 127) * 256 + threadIdx.x;
        const float4 a = ((const float4*)s)[i * 2 + 0];
        const float4 b = ((const float4*)s)[i * 2 + 1];
        uint4 o;
        o.x = pkbf(a.x, a.y); o.y = pkbf(a.z, a.w);
        o.z = pkbf(b.x, b.y); o.w = pkbf(b.z, b.w);
        *(uint4*)(d + (size_t)i * 8) = o;
    }
}

// ---------------------------------------------------------------------------
// GEMM core (round-7 proven) — used by gemm_out only now.
// NOTE (round-6): no XCD remap on GEMM grids (FETCH 29->100MB, +15us).
// NOTE (rounds 3/8/11): BK=64 dbuf, counted-vmcnt, single-barrier 2-phase
// all null on this 4-wave 128^2 shape (T3/T4 regime gate). Keep 2-barrier.
// ---------------------------------------------------------------------------
#define GEMM_CORE(Aptr, Wptr, M0, N0)                                                   \
    __shared__ ushort_t SH[2][128 * 32];                                                \
    ushort_t* const As = SH[0];                                                         \
    ushort_t* const Bs = SH[1];                                                         \
    const int tid = threadIdx.x;                                                        \
    const int lane = tid & 63, wid = tid >> 6;                                          \
    const int quad = lane >> 4, l15 = lane & 15;                                        \
    const int m0 = (M0), n0 = (N0);                                                     \
    const int wy = wid >> 1, wx = wid & 1;                                              \
    floatx4 acc[4][4];                                                                  \
    _Pragma("unroll") for (int i = 0; i < 4; ++i)                                       \
        _Pragma("unroll") for (int j = 0; j < 4; ++j)                                   \
            _Pragma("unroll") for (int r = 0; r < 4; ++r) acc[i][j][r] = 0.f;           \
    for (int k0 = 0; k0 < DDIM; k0 += 32) {                                             \
        __syncthreads();                                                                \
        _Pragma("unroll") for (int j = 0; j < 4; ++j) {                                 \
            const int t = wid * 4 + j;                                                  \
            const int rowi = ((t & 7) << 4) + (lane >> 2);                              \
            const int cd = (lane & 3) ^ ((rowi >> 1) & 3);                              \
            if (t < 8)                                                                  \
                gl_lds16(Aptr + (size_t)(m0 + rowi) * DDIM + k0 + cd * 8,               \
                         (char*)As + ((t & 7) << 10));                                  \
            else                                                                        \
                gl_lds16(Wptr + (size_t)(n0 + rowi) * DDIM + k0 + cd * 8,               \
                         (char*)Bs + ((t & 7) << 10));                                  \
        }                                                                               \
        __syncthreads();                                                                \
        short8 aw[4], bt[4];                                                            \
        _Pragma("unroll") for (int fi = 0; fi < 4; ++fi) {                              \
            const int r = wy * 64 + fi * 16 + l15;                                      \
            aw[fi] = *(const short8*)((const char*)Bs + r * 64 +                        \
                                      ((quad ^ ((r >> 1) & 3)) << 4));                  \
        }                                                                               \
        _Pragma("unroll") for (int ti = 0; ti < 4; ++ti) {                              \
            const int r = wx * 64 + ti * 16 + l15;                                      \
            bt[ti] = *(const short8*)((const char*)As + r * 64 +                        \
                                      ((quad ^ ((r >> 1) & 3)) << 4));                  \
        }                                                                               \
        _Pragma("unroll") for (int fi = 0; fi < 4; ++fi)                                \
            _Pragma("unroll") for (int ti = 0; ti < 4; ++ti)                            \
                acc[fi][ti] = __builtin_amdgcn_mfma_f32_16x16x32_bf16(                  \
                    aw[fi], bt[ti], acc[fi][ti], 0, 0, 0);                              \
    }

// ---------------------------------------------------------------------------
// Merged QKV projection (round-13): ONE pass computes Q, K, V for a
// 128-token x 128-feature tile. Per K-step: stage A once (8KB) + Wq/Wk/Wv
// tiles (24KB) -> 48 MFMA/wave (bt from A reused across the 3 W) vs 16
// before. Staging stalls per MFMA drop ~3x; A fetched from HBM/L3 once
// instead of 3x. acc[3][4][4]=192 VGPR; waves_per_eu(2,2) -> 256 budget.
// Epilogues: Q,K direct bf16; V via the proven 16KB LDS transpose (acc[2]).
// ---------------------------------------------------------------------------
__global__ __launch_bounds__(256)
__attribute__((amdgpu_waves_per_eu(2, 2)))
void gemm_qkv(
    const ushort_t* __restrict__ A,
    const ushort_t* __restrict__ W0, const ushort_t* __restrict__ W1,
    const ushort_t* __restrict__ W2,
    const float* __restrict__ b0, const float* __restrict__ b1,
    const float* __restrict__ b2,
    ushort_t* __restrict__ o0, ushort_t* __restrict__ o1, ushort_t* __restrict__ o2) {
    __shared__ ushort_t SH[4][128 * 32];    // [0]=A tile, [1..3]=Wq/Wk/Wv tiles
    const int tid = threadIdx.x;
    const int lane = tid & 63, wid = tid >> 6;
    const int quad = lane >> 4, l15 = lane & 15;
    const int m0 = blockIdx.x * 128, n0 = blockIdx.y * 128;
    const int wy = wid >> 1, wx = wid & 1;

    floatx4 acc[3][4][4];
    #pragma unroll
    for (int w = 0; w < 3; ++w)
        #pragma unroll
        for (int i = 0; i < 4; ++i)
            #pragma unroll
            for (int j = 0; j < 4; ++j)
                #pragma unroll
                for (int r = 0; r < 4; ++r) acc[w][i][j][r] = 0.f;

    // wave wid stages matrix wid: 0=A (rows m0+), 1..3=W (rows n0+)
    const ushort_t* const stage_src =
        (wid == 0) ? A : (wid == 1 ? W0 : (wid == 2 ? W1 : W2));
    const int stage_base = (wid == 0) ? m0 : n0;

    for (int k0 = 0; k0 < DDIM; k0 += 32) {
        __syncthreads();
        #pragma unroll
        for (int j = 0; j < 8; ++j) {       // 8 x 1KB wave-loads = full 8KB tile
            const int rowi = (j << 4) + (lane >> 2);
            const int cd = (lane & 3) ^ ((rowi >> 1) & 3);
            gl_lds16(stage_src + (size_t)(stage_base + rowi) * DDIM + k0 + cd * 8,
                     (char*)&SH[wid][0] + (j << 10));
        }
        __syncthreads();
        short8 bt[4];
        #pragma unroll
        for (int ti = 0; ti < 4; ++ti) {
            const int r = wx * 64 + ti * 16 + l15;
            bt[ti] = *(const short8*)((const char*)&SH[0][0] + r * 64 +
                                      ((quad ^ ((r >> 1) & 3)) << 4));
        }
        #pragma unroll
        for (int w = 0; w < 3; ++w) {
            short8 aw[4];
            #pragma unroll
            for (int fi = 0; fi < 4; ++fi) {
                const int r = wy * 64 + fi * 16 + l15;
                aw[fi] = *(const short8*)((const char*)&SH[1 + w][0] + r * 64 +
                                          ((quad ^ ((r >> 1) & 3)) << 4));
            }
            #pragma unroll
            for (int fi = 0; fi < 4; ++fi)
                #pragma unroll
                for (int ti = 0; ti < 4; ++ti)
                    acc[w][fi][ti] = __builtin_amdgcn_mfma_f32_16x16x32_bf16(
                        aw[fi], bt[ti], acc[w][fi][ti], 0, 0, 0);
        }
    }

    // ---- Q and K epilogues (direct bf16 [token][512]) ----
    #pragma unroll
    for (int w = 0; w < 2; ++w) {
        const float* const bias = w ? b1 : b0;
        ushort_t* const dst = w ? o1 : o0;
        #pragma unroll
        for (int fi = 0; fi < 4; ++fi) {
            const int f = n0 + wy * 64 + fi * 16 + quad * 4;
            const float4 b4 = *(const float4*)&bias[f];
            #pragma unroll
            for (int ti = 0; ti < 4; ++ti) {
                const int token = m0 + wx * 64 + ti * 16 + l15;
                const float v0 = acc[w][fi][ti][0] + b4.x, v1 = acc[w][fi][ti][1] + b4.y;
                const float v2 = acc[w][fi][ti][2] + b4.z, v3 = acc[w][fi][ti][3] + b4.w;
                uint2 v;
                v.x = pkbf(v0, v1); v.y = pkbf(v2, v3);
                *(uint2*)&dst[(size_t)token * DDIM + f] = v;
            }
        }
    }

    // ---- V epilogue: fp16 Vt[(b*8+h)*64+d][token] via 16KB LDS transpose ----
    {
        const int b = m0 >> 9;            // batch (tile within one b)
        const int hh0 = n0 >> 6;          // head of wy==0 half
        ushort_t* const SHT = &SH[0][0];  // 16KB = [64][128] fp16, chunk-swizzled
        __syncthreads();                  // all K-loop LDS reads complete
        #pragma unroll
        for (int hp = 0; hp < 2; ++hp) {
            if (wy == hp) {
                #pragma unroll
                for (int fi = 0; fi < 4; ++fi) {
                    const int f = n0 + wy * 64 + fi * 16 + quad * 4;
                    const float4 b4 = *(const float4*)&b2[f];
                    #pragma unroll
                    for (int ti = 0; ti < 4; ++ti) {
                        const int q = wx * 64 + ti * 16 + l15;
                        const int qc = q >> 3, qr = q & 7;
                        const float vv[4] = {acc[2][fi][ti][0] + b4.x,
                                             acc[2][fi][ti][1] + b4.y,
                                             acc[2][fi][ti][2] + b4.z,
                                             acc[2][fi][ti][3] + b4.w};
                        #pragma unroll
                        for (int r = 0; r < 4; ++r) {
                            const int d = fi * 16 + quad * 4 + r;
                            SHT[(d * 256 + ((qc ^ (d & 15)) << 4) + qr * 2) >> 1] =
                                __half_as_ushort(__float2half(vv[r]));
                        }
                    }
                }
            }
            __syncthreads();
            const size_t vbase = ((size_t)(b * HH + hh0 + hp)) * DK;
            #pragma unroll
            for (int c = 0; c < 4; ++c) {
                const int ch = tid + 256 * c;           // [0,1024)
                const int d = ch >> 4, chl = ch & 15;
                const uint4 vv = *(const uint4*)((const char*)SHT + d * 256 +
                                                 ((chl ^ (d & 15)) << 4));
                *(uint4*)&o2[(vbase + d) * NN + (m0 & 511) + chl * 8] = vv;
            }
            __syncthreads();
        }
    }
}

// Output projection -> fp32 [token][512]
__global__ __launch_bounds__(256) void gemm_out(
    const ushort_t* __restrict__ A, const ushort_t* __restrict__ Wo,
    const float* __restrict__ bo, float* __restrict__ dst) {
    GEMM_CORE(A, Wo, blockIdx.x * 128, blockIdx.y * 128)
    #pragma unroll
    for (int fi = 0; fi < 4; ++fi) {
        const int f = n0 + wy * 64 + fi * 16 + quad * 4;
        const float4 b4 = *(const float4*)&bo[f];
        #pragma unroll
        for (int ti = 0; ti < 4; ++ti) {
            const int token = m0 + wx * 64 + ti * 16 + l15;
            float4 v;
            v.x = acc[fi][ti][0] + b4.x; v.y = acc[fi][ti][1] + b4.y;
            v.z = acc[fi][ti][2] + b4.z; v.w = acc[fi][ti][3] + b4.w;
            *(float4*)&dst[(size_t)token * DDIM + f] = v;
        }
    }
}

// ---------------------------------------------------------------------------
// Persistent-KV MFMA attention, 32x32 MFMA + in-register P (round-7 form —
// round-12's T-prefetch double-buffer regressed +5us, reverted).
// XCD swizzle (round-7 A/B, -4.4us): h = n&7, b = n>>3 with n = (p%8)*32+p/8
// -> all 8 heads of one b on ONE XCD, T[b] L2-resident.
// ---------------------------------------------------------------------------
__global__ __launch_bounds__(512)
__attribute__((amdgpu_waves_per_eu(2, 2)))
void attn_fused(
    const ushort_t* __restrict__ Qg, const ushort_t* __restrict__ Kg,
    const ushort_t* __restrict__ Vtg, const ushort_t* __restrict__ Tg,
    ushort_t* __restrict__ aout) {
    __shared__ ushort_t Ks[512 * 64];   // 64KB: row kj, 128B, 8x16B grans, gran g = global g^key(kj)
    __shared__ ushort_t Vs[64 * 512];   // 64KB: row d, 1024B, 64 grans, gran g = global g^key(d)

    const int tid = threadIdx.x, lane = tid & 63, wid = tid >> 6;
    const int l31 = lane & 31, hl = lane >> 5;
    const int p = blockIdx.x;
    const int nid = (p & 7) * 32 + (p >> 3);
    const int h = nid & 7, b = nid >> 3;
    const float K1 = 0.18033688f;       // 0.125 * log2(e)

    // ---- stage K + V^T (once) ----
    #pragma unroll
    for (int j = 0; j < 8; ++j) {
        const int t = wid * 8 + j;
        {   // K rows t*8 .. t*8+7 (1KB per wave-load)
            const int row = t * 8 + (lane >> 3);
            const int key = (row & 7) ^ ((row >> 3) & 7);
            const int g = (lane & 7) ^ key;
            gl_lds16(Kg + (size_t)(b * NN + row) * DDIM + h * DK + g * 8,
                     (char*)Ks + t * 1024);
        }
        {   // V^T row d = t (1KB per wave-load)
            const int key = (t & 7) ^ ((t >> 3) & 7);
            const int g = lane ^ key;
            gl_lds16(Vtg + (size_t)((b * HH + h) * DK + t) * NN + g * 8,
                     (char*)Vs + t * 1024);
        }
    }

    // ---- Q fragments (B-operand: n=q=lane&31, k=dk=(lane>>5)*8+j) ----
    short8 bq[2][4];
    #pragma unroll
    for (int qt = 0; qt < 2; ++qt) {
        const ushort_t* qp =
            Qg + (size_t)(b * NN + wid * 64 + qt * 32 + l31) * DDIM + h * DK + hl * 8;
        #pragma unroll
        for (int st = 0; st < 4; ++st) bq[qt][st] = *(const short8*)(qp + st * 16);
    }

    float lsum[2] = {0.f, 0.f};
    floatx16 O[2][2];                    // [qt][dt], C: col=q, row=d
    #pragma unroll
    for (int qt = 0; qt < 2; ++qt)
        #pragma unroll
        for (int dt = 0; dt < 2; ++dt)
            #pragma unroll
            for (int r = 0; r < 16; ++r) O[qt][dt][r] = 0.f;

    __syncthreads();   // the only barrier

    for (int kt = 0; kt < 8; ++kt) {
        // T prefetch: tv[qt][kti][g] covers k = kt*64 + kti*32 + g*8 + hl*4 + 0..3
        uint2 tv[2][2][4];
        #pragma unroll
        for (int qt = 0; qt < 2; ++qt) {
            const ushort_t* tp =
                Tg + (size_t)(b * NN + wid * 64 + qt * 32 + l31) * NN + kt * 64 + hl * 4;
            #pragma unroll
            for (int kti = 0; kti < 2; ++kti)
                #pragma unroll
                for (int g = 0; g < 4; ++g)
                    tv[qt][kti][g] = *(const uint2*)(tp + kti * 32 + g * 8);
        }

        #pragma unroll
        for (int kti = 0; kti < 2; ++kti) {
            // K fragments (A: m=k-row=lane&31(+base), k=dk=(lane>>5)*8+j)
            short8 kf[4];
            {
                const int row = kt * 64 + kti * 32 + l31;
                const int key = (row & 7) ^ ((row >> 3) & 7);
                #pragma unroll
                for (int st = 0; st < 4; ++st)
                    kf[st] = *(const short8*)((const char*)Ks + row * 128 +
                                              (((st * 2 + hl) ^ key) << 4));
            }
            // V^T fragments (A: m=d=lane&31(+dt*32), k=(lane>>5)*8+j)
            half8 vf[2][2];   // [dt][ks]
            #pragma unroll
            for (int dt = 0; dt < 2; ++dt) {
                const int d = dt * 32 + l31;
                const int key = (d & 7) ^ ((d >> 3) & 7);
                #pragma unroll
                for (int ks = 0; ks < 2; ++ks)
                    vf[dt][ks] = *(const half8*)((const char*)Vs + d * 1024 +
                        (((kt * 8 + kti * 4 + ks * 2 + hl) ^ key) << 4));
            }

            #pragma unroll
            for (int qt = 0; qt < 2; ++qt) {
                // S^T tile [32k x 32q] = K.Q^T
                floatx16 S;
                #pragma unroll
                for (int r = 0; r < 16; ++r) S[r] = 0.f;
                __builtin_amdgcn_s_setprio(1);
                #pragma unroll
                for (int st = 0; st < 4; ++st)
                    S = __builtin_amdgcn_mfma_f32_32x32x16_bf16(
                        kf[st], bq[qt][st], S, 0, 0, 0);
                __builtin_amdgcn_s_setprio(0);

                float ls = 0.f;
                #pragma unroll
                for (int ks = 0; ks < 2; ++ks) {       // 16-k PV step
                    float pp[8];
                    #pragma unroll
                    for (int gg = 0; gg < 2; ++gg) {
                        const uint2 tg = tv[qt][kti][ks * 2 + gg];
                        const float t0 = h2f((ushort_t)tg.x);
                        const float t1 = h2f((ushort_t)(tg.x >> 16));
                        const float t2 = h2f((ushort_t)tg.y);
                        const float t3 = h2f((ushort_t)(tg.y >> 16));
                        const int sb = ks * 8 + gg * 4;
                        pp[gg * 4 + 0] = exp2f(S[sb + 0] * K1 + t0);
                        pp[gg * 4 + 1] = exp2f(S[sb + 1] * K1 + t1);
                        pp[gg * 4 + 2] = exp2f(S[sb + 2] * K1 + t2);
                        pp[gg * 4 + 3] = exp2f(S[sb + 3] * K1 + t3);
                        ls += (pp[gg * 4 + 0] + pp[gg * 4 + 1]) +
                              (pp[gg * 4 + 2] + pp[gg * 4 + 3]);
                    }
                    // pack own 8 P vals to fp16, half-exchange to B layout:
                    // lane's pp[gg*4+r] holds k_off = 8*gg + 4*hl + r.
                    // B needs k = 8*hl + j. swap(w0,w2) -> (word0, word2);
                    // swap(w1,w3) -> (word1, word3).
                    uint_t w0 = pkh(pp[0], pp[1]);   // own pk01
                    uint_t w1 = pkh(pp[2], pp[3]);   // own pk23
                    uint_t w2 = pkh(pp[4], pp[5]);   // own pk45
                    uint_t w3 = pkh(pp[6], pp[7]);   // own pk67
                    auto r02 = __builtin_amdgcn_permlane32_swap(w0, w2, false, false);
                    auto r13 = __builtin_amdgcn_permlane32_swap(w1, w3, false, false);
                    uint4 uu;
                    uu.x = r02[0];   // word0 = {w0.lo, w2.lo}
                    uu.y = r13[0];   // word1 = {w1.lo, w3.lo}
                    uu.z = r02[1];   // word2 = {w0.hi, w2.hi}
                    uu.w = r13[1];   // word3 = {w1.hi, w3.hi}
                    const half8 bp = __builtin_bit_cast(half8, uu);

                    __builtin_amdgcn_s_setprio(1);
                    #pragma unroll
                    for (int dt = 0; dt < 2; ++dt)
                        O[qt][dt] = __builtin_amdgcn_mfma_f32_32x32x16_f16(
                            vf[dt][ks], bp, O[qt][dt], 0, 0, 0);
                    __builtin_amdgcn_s_setprio(0);
                }
                lsum[qt] += ls;
            }
        }
    }

    // ---- epilogue: reduce l over lane halves, normalize, write bf16 ----
    #pragma unroll
    for (int qt = 0; qt < 2; ++qt) {
        float l = lsum[qt];
        l += __shfl_xor(l, 32);
        const float inv = 1.0f / l;
        const size_t orow =
            (size_t)(b * NN + wid * 64 + qt * 32 + l31) * DDIM + h * DK;
        #pragma unroll
        for (int dt = 0; dt < 2; ++dt)
            #pragma unroll
            for (int g = 0; g < 4; ++g) {
                const int d = dt * 32 + g * 8 + hl * 4;
                uint2 ov;
                ov.x = pkbf(O[qt][dt][g * 4 + 0] * inv, O[qt][dt][g * 4 + 1] * inv);
                ov.y = pkbf(O[qt][dt][g * 4 + 2] * inv, O[qt][dt][g * 4 + 3] * inv);
                *(uint2*)&aout[orow + d] = ov;
            }
    }
}

extern "C" void kernel_launch(void* const* d_in, const int* in_sizes, int n_in,
                              void* d_out, int out_size, void* d_ws, size_t ws_size,
                              hipStream_t stream) {
    const float* x    = (const float*)d_in[0];
    const float* dist = (const float*)d_in[1];
    const float* Wq   = (const float*)d_in[2];
    const float* bq   = (const float*)d_in[3];
    const float* Wk   = (const float*)d_in[4];
    const float* bk   = (const float*)d_in[5];
    const float* Wv   = (const float*)d_in[6];
    const float* bv   = (const float*)d_in[7];
    const float* Wo   = (const float*)d_in[8];
    const float* bo   = (const float*)d_in[9];
    const float* dw   = (const float*)d_in[10];
    float* out = (float*)d_out;

    const size_t NELT = (size_t)BB * NN * DDIM;   // 8388608
    ushort_t* xb  = (ushort_t*)d_ws;              // x bf16; aliased by ab later
    ushort_t* wqb = xb + NELT;
    ushort_t* wkb = wqb + DDIM * DDIM;
    ushort_t* wvb = wkb + DDIM * DDIM;
    ushort_t* wob = wvb + DDIM * DDIM;
    ushort_t* qb  = wob + DDIM * DDIM;
    ushort_t* kb  = qb + NELT;
    ushort_t* vt  = kb + NELT;                    // fp16, transposed (written by gemm_qkv)
    ushort_t* Tm  = vt + NELT;                    // fp16 bias matrix
    ushort_t* ab  = xb;                           // alias: xb dead after gemm_qkv

    prep_all<<<8704, 256, 0, stream>>>(x, dist, dw, Wq, Wk, Wv, Wo,
                                       xb, Tm, wqb, wkb, wvb, wob);
    gemm_qkv<<<dim3(128, 4), 256, 0, stream>>>(xb, wqb, wkb, wvb, bq, bk, bv,
                                               qb, kb, vt);
    attn_fused<<<256, 512, 0, stream>>>(qb, kb, vt, Tm, ab);
    gemm_out<<<dim3(128, 4), 256, 0, stream>>>(ab, wob, bo, out);
}